// Round 9
// baseline (588.167 us; speedup 1.0000x reference)
//
#include <hip/hip_runtime.h>
#include <hip/hip_bf16.h>

// x [B=2, C=16, T=31, H=256, W=256] fp32
#define TDIM 31
#define TS   65536                 // t stride (H*W)
#define CS   (TDIM * TS)           // c stride = 2,031,616
#define BS   (16 * CS)             // b stride
#define NTOT (2 * BS)              // 65,011,712
#define K1_BLOCKS 8192             // 16 positions per block
#define GAP_INV (1.0f / (31.0f * 65536.0f))

typedef __attribute__((ext_vector_type(8))) short short8v;     // 8 bf16 (4 VGPR)
typedef __attribute__((ext_vector_type(4))) float f32x4;       // MFMA C/D
typedef __attribute__((ext_vector_type(8))) unsigned short ushort8v;

__device__ __forceinline__ float frcp(float v){ return __builtin_amdgcn_rcpf(v); }
__device__ __forceinline__ float fexp2_(float v){ return __builtin_amdgcn_exp2f(v); }
__device__ __forceinline__ float ftanh(float x){ float e = fexp2_(x*2.8853900817779268f); return 1.0f - 2.0f*frcp(e+1.0f); }
__device__ __forceinline__ float fsigm(float x){ float e = fexp2_(x*-1.4426950408889634f); return frcp(1.0f+e); }
__device__ __forceinline__ unsigned rhu16(float x){ return (__float_as_uint(x) + 0x8000u) >> 16; }
__device__ __forceinline__ float bf2f(unsigned b){ return __uint_as_float(b << 16); }
// pack [hi16(x1) : hi16(x0)] in one v_perm
__device__ __forceinline__ unsigned pkhi(unsigned u0, unsigned u1){ return __builtin_amdgcn_perm(u1, u0, 0x07060302u); }

// Block: 16 positions x all 31 timesteps, 512 threads = 8 waves (TLP 2x vs r7:
// r2..r7 showed k1 pinned ~250us with VALUBusy<=47% and ~3 waves/SIMD -> the
// bound is latency coverage, not issue/conflicts/prefetch. 8 waves/block at
// VGPR<=64 gives 4 blocks x 8 = 32 waves/CU.)
// Phase 1: wave wv handles units u = wv, wv+8, wv+16, wv+24 (unit = one t of
//   16 positions; wave 7 has 3 units). 2-buffer register prefetch. Per unit:
//   B=[Xhi;Xlo] K-split MFMAs for conv1 (both branches, bias as C-init), tanh,
//   conv1->conv2 transpose via 8 in-wave shuffles (no LDS), conv2 = 2 MFMAs,
//   (z,f) snorm16/unorm16 -> 4 b32 writes into bank-swizzled gate array
//   (max 2 lanes/bank = conflict-free).
// Phase 2: threads 0..255, thread (c,p) scans 31 steps, one conflict-free b32
//   read per t, stores h (bf16 to ws or f32 to out), GAP partials.
//
// Gate LDS layout (bijective, bank-proven):
//   idx(t,p,c) = t*256 + (c&3)*64 + ((c>>3)&1)*32 + ((c^(c>>2))&1)*16
//              + ((p + 4*c) & 15)
// NOTE: (512,8) caps VGPR at 64. Spill sentinel = WRITE_SIZE >> 127 MB.
template<bool BF16H>
__global__ __launch_bounds__(512, 8) void k1_fused(
    const float* __restrict__ x,
    const float* __restrict__ wf1, const float* __restrict__ bf1,
    const float* __restrict__ wf2, const float* __restrict__ bf2,
    const float* __restrict__ ww1, const float* __restrict__ bw1,
    const float* __restrict__ ww2, const float* __restrict__ bw2,
    float* __restrict__ out, unsigned short* __restrict__ hb,
    float* __restrict__ partials)
{
    __shared__ unsigned int sGate[TDIM * 256];       // 31744 B

    const int tid  = threadIdx.x;
    const int lane = tid & 63;
    const int wv   = tid >> 6;             // 0..7
    const int col  = lane & 15;            // A-row (=o) / B-col (=position)
    const int kg   = lane >> 4;            // k-group: k = kg*8 + i
    const bool lok = (kg >= 2);            // this lane's B-elems are lo-residuals
    const int blk  = blockIdx.x;
    const int b    = blk >> 12;            // 4096 blocks per batch
    const int p0   = (blk & 4095) << 4;

    // ---- weight A-fragments (built once; K=32 logical) ----
    short8v A1f, A2f, A1w, A2w, Af2, Aw2;
    {
        const int c0 = (kg & 1) * 8;       // kg0/2 -> cols 0-7, kg1/3 -> 8-15
#pragma unroll
        for (int i = 0; i < 8; ++i) {
            const float w1 = wf1[col*16 + c0 + i];
            unsigned u1 = __float_as_uint(w1);
            float lo1 = w1 - __uint_as_float(u1 & 0xFFFF0000u);
            A1f[i] = (short)(u1 >> 16);
            A2f[i] = (short)(__float_as_uint(lo1) >> 16);
            const float w2 = ww1[col*16 + c0 + i];
            unsigned u2 = __float_as_uint(w2);
            float lo2 = w2 - __uint_as_float(u2 & 0xFFFF0000u);
            A1w[i] = (short)(u2 >> 16);
            A2w[i] = (short)(__float_as_uint(lo2) >> 16);
            const float v2f = wf2[col*16 + c0 + i];
            const float v2w = ww2[col*16 + c0 + i];
            Af2[i] = (kg < 2)  ? (short)rhu16(v2f) : (short)0;   // [Wf2 | 0]
            Aw2[i] = (kg >= 2) ? (short)rhu16(v2w) : (short)0;   // [0 | Ww2]
        }
    }
    f32x4 b1fv, b1wv, b2fv, b2wv;          // bias vectors: D row o = kg*4 + r
#pragma unroll
    for (int r = 0; r < 4; ++r) {
        b1fv[r] = bf1[kg*4+r]; b1wv[r] = bw1[kg*4+r];
        b2fv[r] = bf2[kg*4+r]; b2wv[r] = bw2[kg*4+r];
    }

    const int lsrc = col + ((kg & 1) << 5);  // col + ((kg&1)*2)*16

    auto process = [&](int u, const float* xv) {
        // B-frag: k<16 -> Xhi (trunc), k>=16 -> Xlo (residual); v_perm packing
        unsigned H[4], L[4];
#pragma unroll
        for (int j = 0; j < 4; ++j) {
            const unsigned u0 = __float_as_uint(xv[2*j]);
            const unsigned u1 = __float_as_uint(xv[2*j+1]);
            const float l0 = xv[2*j]   - __uint_as_float(u0 & 0xFFFF0000u);
            const float l1 = xv[2*j+1] - __uint_as_float(u1 & 0xFFFF0000u);
            H[j] = pkhi(u0, u1);
            L[j] = pkhi(__float_as_uint(l0), __float_as_uint(l1));
        }
        uint4 bxu;
        bxu.x = lok ? L[0] : H[0]; bxu.y = lok ? L[1] : H[1];
        bxu.z = lok ? L[2] : H[2]; bxu.w = lok ? L[3] : H[3];
        const short8v bx = __builtin_bit_cast(short8v, bxu);

        f32x4 accf = b1fv, accw = b1wv;    // bias as C-init
        accf = __builtin_amdgcn_mfma_f32_16x16x32_bf16(A1f, bx, accf, 0, 0, 0);
        accf = __builtin_amdgcn_mfma_f32_16x16x32_bf16(A2f, bx, accf, 0, 0, 0);
        accw = __builtin_amdgcn_mfma_f32_16x16x32_bf16(A1w, bx, accw, 0, 0, 0);
        accw = __builtin_amdgcn_mfma_f32_16x16x32_bf16(A2w, bx, accw, 0, 0, 0);

        // activations, packed bf16 pairs per (kg): channels kg*4+{0,1},{2,3}
        const float a0 = ftanh(accf[0]), a1 = ftanh(accf[1]);
        const float a2 = ftanh(accf[2]), a3 = ftanh(accf[3]);
        const float w0 = ftanh(accw[0]), w1 = ftanh(accw[1]);
        const float w2 = ftanh(accw[2]), w3 = ftanh(accw[3]);
        const unsigned afP0 = (rhu16(a1) << 16) | rhu16(a0);
        const unsigned afP1 = (rhu16(a3) << 16) | rhu16(a2);
        const unsigned awP0 = (rhu16(w1) << 16) | rhu16(w0);
        const unsigned awP1 = (rhu16(w3) << 16) | rhu16(w2);

        // conv1->conv2 transpose: 8 in-wave shuffles (ds_bpermute), no LDS.
        const unsigned x0l = __shfl(afP0, lsrc, 64);
        const unsigned x1l = __shfl(afP1, lsrc, 64);
        const unsigned x0h = __shfl(afP0, lsrc + 16, 64);
        const unsigned x1h = __shfl(afP1, lsrc + 16, 64);
        const unsigned y0l = __shfl(awP0, lsrc, 64);
        const unsigned y1l = __shfl(awP1, lsrc, 64);
        const unsigned y0h = __shfl(awP0, lsrc + 16, 64);
        const unsigned y1h = __shfl(awP1, lsrc + 16, 64);
        uint4 b2u;
        b2u.x = lok ? y0l : x0l;           // B2 = [af ; aw] along K
        b2u.y = lok ? y1l : x1l;
        b2u.z = lok ? y0h : x0h;
        b2u.w = lok ? y1h : x1h;
        const short8v b2 = __builtin_bit_cast(short8v, b2u);

        f32x4 acz = b2fv, acw = b2wv;
        acz = __builtin_amdgcn_mfma_f32_16x16x32_bf16(Af2, b2, acz, 0, 0, 0);
        acw = __builtin_amdgcn_mfma_f32_16x16x32_bf16(Aw2, b2, acw, 0, 0, 0);

        // quantize (z snorm16 | f unorm16) -> 4 swizzled b32 writes (2-way max)
#pragma unroll
        for (int r = 0; r < 4; ++r) {
            const float z = ftanh(acz[r]);
            const float f = fsigm(acw[r]);
            const int   zi = (int)__builtin_rintf(z * 32767.0f);
            const unsigned fu = (unsigned)(f * 65535.0f + 0.5f);
            const unsigned wd = ((unsigned)zi << 16) | (fu & 0xFFFFu);
            sGate[u*256 + r*64 + (kg>>1)*32 + (((r ^ kg) & 1) << 4)
                  + ((col + 4*r) & 15)] = wd;
        }
    };

    // ---- phase 1: units wv, wv+8, wv+16, wv+24 with 2-buffer prefetch ----
    const unsigned xbase = (unsigned)b * BS + (unsigned)p0 + (unsigned)col
                         + (unsigned)((kg & 1) * 8) * CS;
#define LOADU(dst, u_) { const float* xp = x + (size_t)xbase + (size_t)(u_) * TS; \
    _Pragma("unroll") for (int i = 0; i < 8; ++i) (dst)[i] = xp[i * CS]; }

    {
        float xa[8], xb_[8];
        LOADU(xa,  wv)                    // u0 = wv       (< 31 always)
        LOADU(xb_, wv + 8)                // u1 = wv+8     (<= 15)
        process(wv, xa);
        LOADU(xa,  wv + 16)               // u2 = wv+16    (<= 23)
        process(wv + 8, xb_);
        if (wv < 7) {
            LOADU(xb_, wv + 24)           // u3 = wv+24    (<= 30 only if wv<7)
            process(wv + 16, xa);
            process(wv + 24, xb_);
        } else {
            process(wv + 16, xa);
        }
    }
#undef LOADU
    __syncthreads();

    // ---- phase 2: threads 0..255, thread = (c, p), one channel each ----
    if (tid < 256) {
        const int c = tid >> 4, p = tid & 15;
        const unsigned base2 = (unsigned)((c & 3) * 64 + ((c >> 3) & 1) * 32
                             + (((c ^ (c >> 2)) & 1) << 4) + ((p + 4 * c) & 15));
        const unsigned obase = (unsigned)b * BS + (unsigned)c * CS
                             + (unsigned)p0 + (unsigned)p;
        float h = 0.f, s = 0.f;
#pragma unroll 1
        for (int t = 0; t < TDIM; ++t) {
            const unsigned wd = sGate[t * 256 + base2];
            const float z = (float)((int)wd >> 16) * (1.0f / 32767.0f);
            const float f = (float)(wd & 0xFFFFu) * (1.0f / 65535.0f);
            h = fmaf(f, h - z, z);          // f*h + (1-f)*z
            s += h;
            if (BF16H) hb[obase + (unsigned)t * TS] = (unsigned short)rhu16(h);
            else       out[obase + (unsigned)t * TS] = h;
        }
#pragma unroll
        for (int off = 8; off; off >>= 1) s += __shfl_down(s, off, 16);
        if (p == 0) partials[blk * 16 + c] = s;
    }
}

__global__ __launch_bounds__(1024) void k2_attention(
    const float* __restrict__ partials, const float* __restrict__ wsca,
    const float* __restrict__ bsca, float* __restrict__ att)
{
    __shared__ float red[2][16][32];
    __shared__ float gap[2][16];
    const int tid = threadIdx.x;
    {
        const int b = tid >> 9, c = (tid >> 5) & 15, seg = tid & 31;
        float s = 0.f;
        const float* p = partials + (size_t)(b * 4096 + seg * 128) * 16 + c;
        for (int j = 0; j < 128; ++j) s += p[j * 16];
        red[b][c][seg] = s;
    }
    __syncthreads();
    if (tid < 32) {
        const int b = tid >> 4, c = tid & 15;
        float s = 0.f;
#pragma unroll
        for (int g = 0; g < 32; ++g) s += red[b][c][g];
        gap[b][c] = s * GAP_INV;
    }
    __syncthreads();
    if (tid < 32) {
        const int b = tid >> 4, o = tid & 15;
        float acc = bsca[o];
#pragma unroll
        for (int c = 0; c < 16; ++c) acc = fmaf(wsca[o*16 + c], gap[b][c], acc);
        att[b*16 + o] = fsigm(acc);
    }
}

// bf16-h path: read h (bf16, ws), write fp32 out. grid (248, 32) x 1024: exact.
__global__ __launch_bounds__(1024) void k3_scale_b(
    const unsigned short* __restrict__ hb, const float* __restrict__ att,
    float* __restrict__ out)
{
    const int bc = blockIdx.y;
    const float a = att[bc];
    const unsigned i = blockIdx.x * 1024 + threadIdx.x;     // < 253,952 = CS/8
    const size_t base = (size_t)bc * CS;
    const ushort8v v = ((const ushort8v*)(hb + base))[i];
    float4 o1, o2;
    o1.x = bf2f(v[0])*a; o1.y = bf2f(v[1])*a; o1.z = bf2f(v[2])*a; o1.w = bf2f(v[3])*a;
    o2.x = bf2f(v[4])*a; o2.y = bf2f(v[5])*a; o2.z = bf2f(v[6])*a; o2.w = bf2f(v[7])*a;
    float4* op = (float4*)(out + base);
    op[i*2]     = o1;
    op[i*2 + 1] = o2;
}

// fallback: in-place fp32 scale
__global__ __launch_bounds__(1024) void k3_scale_a(
    const float* __restrict__ att, float* __restrict__ out)
{
    const int bc = blockIdx.y;
    const float a = att[bc];
    const unsigned i = blockIdx.x * 1024 + threadIdx.x;
    float4* op = (float4*)(out + (size_t)bc * CS);
    float4 v1 = op[i*2], v2 = op[i*2 + 1];
    v1.x *= a; v1.y *= a; v1.z *= a; v1.w *= a;
    v2.x *= a; v2.y *= a; v2.z *= a; v2.w *= a;
    op[i*2] = v1; op[i*2 + 1] = v2;
}

extern "C" void kernel_launch(void* const* d_in, const int* in_sizes, int n_in,
                              void* d_out, int out_size, void* d_ws, size_t ws_size,
                              hipStream_t stream) {
    const float* x    = (const float*)d_in[0];
    const float* wf1  = (const float*)d_in[1];
    const float* bf1  = (const float*)d_in[2];
    const float* wf2  = (const float*)d_in[3];
    const float* bf2  = (const float*)d_in[4];
    const float* ww1  = (const float*)d_in[5];
    const float* bw1  = (const float*)d_in[6];
    const float* ww2  = (const float*)d_in[7];
    const float* bw2  = (const float*)d_in[8];
    const float* wsca = (const float*)d_in[9];
    const float* bsca = (const float*)d_in[10];
    float* out = (float*)d_out;

    const size_t hbBytes   = (size_t)NTOT * 2;               // 130,023,424
    const size_t partBytes = (size_t)K1_BLOCKS * 16 * 4;     // 524,288
    const bool bf16h = ws_size >= hbBytes + partBytes + 256;

    unsigned short* hb = (unsigned short*)d_ws;
    float* partials = bf16h ? (float*)((char*)d_ws + hbBytes) : (float*)d_ws;
    float* att = partials + K1_BLOCKS * 16;

    if (bf16h) {
        k1_fused<true><<<K1_BLOCKS, 512, 0, stream>>>(x, wf1, bf1, wf2, bf2,
            ww1, bw1, ww2, bw2, out, hb, partials);
        k2_attention<<<1, 1024, 0, stream>>>(partials, wsca, bsca, att);
        k3_scale_b<<<dim3(248, 32), 1024, 0, stream>>>(hb, att, out);
    } else {
        k1_fused<false><<<K1_BLOCKS, 512, 0, stream>>>(x, wf1, bf1, wf2, bf2,
            ww1, bw1, ww2, bw2, out, hb, partials);
        k2_attention<<<1, 1024, 0, stream>>>(partials, wsca, bsca, att);
        k3_scale_a<<<dim3(248, 32), 1024, 0, stream>>>(att, out);
    }
}

// Round 10
// 332.327 us; speedup vs baseline: 1.7698x; 1.7698x over previous
//
#include <hip/hip_runtime.h>
#include <hip/hip_bf16.h>

// x [B=2, C=16, T=31, H=256, W=256] fp32
#define TDIM 31
#define TS   65536                 // t stride (H*W)
#define CS   (TDIM * TS)           // c stride = 2,031,616
#define BS   (16 * CS)             // b stride
#define NTOT (2 * BS)              // 65,011,712
#define GAP_INV (1.0f / (31.0f * 65536.0f))

typedef __attribute__((ext_vector_type(8))) unsigned short ushort8v;

__device__ __forceinline__ float frcp(float v){ return __builtin_amdgcn_rcpf(v); }
__device__ __forceinline__ float fexp2_(float v){ return __builtin_amdgcn_exp2f(v); }
__device__ __forceinline__ float ftanh(float x){ float e = fexp2_(x*2.8853900817779268f); return 1.0f - 2.0f*frcp(e+1.0f); }
__device__ __forceinline__ float fsigm(float x){ float e = fexp2_(x*-1.4426950408889634f); return frcp(1.0f+e); }
__device__ __forceinline__ unsigned rhu16(float x){ return (__float_as_uint(x) + 0x8000u) >> 16; }
__device__ __forceinline__ float bf2f(unsigned b){ return __uint_as_float(b << 16); }

// ---------------- kA: gates (pure streaming, t-parallel) ----------------
// Thread = one (b, t, pos). All 16 channels in registers; weights via LDS
// float4 broadcast (wave-uniform address, conflict-free). Writes packed
// (z snorm16 | f unorm16) u32 into `gates` (= d_out used as scratch; k3
// overwrites it completely afterwards). Layout identical to x -> both the
// 16 stride-CS loads and stores coalesce to 256 B per wave instruction.
__global__ __launch_bounds__(256) void kA_gates(
    const float* __restrict__ x,
    const float* __restrict__ wf1, const float* __restrict__ bf1,
    const float* __restrict__ wf2, const float* __restrict__ bf2,
    const float* __restrict__ ww1, const float* __restrict__ bw1,
    const float* __restrict__ ww2, const float* __restrict__ bw2,
    unsigned int* __restrict__ gates)
{
    __shared__ float sW[4][256];          // wf1, ww1, wf2, ww2 (row-major [o][c])
    __shared__ float sB[4][16];

    const int tid = threadIdx.x;
    sW[0][tid] = wf1[tid]; sW[1][tid] = ww1[tid];
    sW[2][tid] = wf2[tid]; sW[3][tid] = ww2[tid];
    if (tid < 16) {
        sB[0][tid] = bf1[tid]; sB[1][tid] = bw1[tid];
        sB[2][tid] = bf2[tid]; sB[3][tid] = bw2[tid];
    }
    __syncthreads();

    const int pos = blockIdx.x * 256 + tid;     // 0..65535
    const int t   = blockIdx.y;                 // 0..30
    const int b   = blockIdx.z;                 // 0..1
    const unsigned base = (unsigned)b * BS + (unsigned)t * TS + (unsigned)pos;

    float xv[16];
#pragma unroll
    for (int c = 0; c < 16; ++c) xv[c] = x[base + (unsigned)c * CS];

    // conv1 (both branches) + tanh
    float af[16], aw[16];
#pragma unroll
    for (int o = 0; o < 16; ++o) {
        float a1 = sB[0][o], a2 = sB[1][o];
#pragma unroll
        for (int q = 0; q < 4; ++q) {
            const float4 w1 = *(const float4*)&sW[0][o * 16 + q * 4];
            const float4 w2 = *(const float4*)&sW[1][o * 16 + q * 4];
            a1 = fmaf(w1.x, xv[q*4+0], a1); a1 = fmaf(w1.y, xv[q*4+1], a1);
            a1 = fmaf(w1.z, xv[q*4+2], a1); a1 = fmaf(w1.w, xv[q*4+3], a1);
            a2 = fmaf(w2.x, xv[q*4+0], a2); a2 = fmaf(w2.y, xv[q*4+1], a2);
            a2 = fmaf(w2.z, xv[q*4+2], a2); a2 = fmaf(w2.w, xv[q*4+3], a2);
        }
        af[o] = ftanh(a1);
        aw[o] = ftanh(a2);
    }
    // conv2 (both branches) -> z=tanh, f=sigm -> pack -> store
#pragma unroll
    for (int o = 0; o < 16; ++o) {
        float a1 = sB[2][o], a2 = sB[3][o];
#pragma unroll
        for (int q = 0; q < 4; ++q) {
            const float4 w1 = *(const float4*)&sW[2][o * 16 + q * 4];
            const float4 w2 = *(const float4*)&sW[3][o * 16 + q * 4];
            a1 = fmaf(w1.x, af[q*4+0], a1); a1 = fmaf(w1.y, af[q*4+1], a1);
            a1 = fmaf(w1.z, af[q*4+2], a1); a1 = fmaf(w1.w, af[q*4+3], a1);
            a2 = fmaf(w2.x, aw[q*4+0], a2); a2 = fmaf(w2.y, aw[q*4+1], a2);
            a2 = fmaf(w2.z, aw[q*4+2], a2); a2 = fmaf(w2.w, aw[q*4+3], a2);
        }
        const float z = ftanh(a1);
        const float f = fsigm(a2);
        const int zi = (int)__builtin_rintf(z * 32767.0f);
        const unsigned fu = (unsigned)(f * 65535.0f + 0.5f);
        gates[base + (unsigned)o * CS] = ((unsigned)zi << 16) | (fu & 0xFFFFu);
    }
}

// ---------------- kB: scan over t (pure streaming) ----------------
// Thread = one (b, c, pos). 31 independent stride-TS gate loads (pipelined),
// register h-chain, h stored bf16 to ws (or f32 in-place over gates when ws
// is too small). Wave-level GAP partial per (b,c).
template<bool BF16H>
__global__ __launch_bounds__(256) void kB_scan(
    unsigned int* __restrict__ gates,       // also f32 h output when !BF16H
    unsigned short* __restrict__ hb,
    float* __restrict__ partials)
{
    const int pos = blockIdx.x * 256 + threadIdx.x;   // 0..65535
    const int c   = blockIdx.y;                       // 0..15
    const int b   = blockIdx.z;                       // 0..1
    const unsigned base = (unsigned)b * BS + (unsigned)c * CS + (unsigned)pos;

    float h = 0.f, s = 0.f;
#pragma unroll
    for (int t = 0; t < TDIM; ++t) {
        const unsigned wd = gates[base + (unsigned)t * TS];
        const float z = (float)((int)wd >> 16) * (1.0f / 32767.0f);
        const float f = (float)(wd & 0xFFFFu) * (1.0f / 65535.0f);
        h = fmaf(f, h - z, z);              // f*h + (1-f)*z
        s += h;
        if (BF16H) hb[base + (unsigned)t * TS] = (unsigned short)rhu16(h);
        else       ((float*)gates)[base + (unsigned)t * TS] = h;   // in-place
    }
#pragma unroll
    for (int off = 32; off; off >>= 1) s += __shfl_down(s, off, 64);
    const int lane = threadIdx.x & 63, wv = threadIdx.x >> 6;
    if (lane == 0)
        partials[(unsigned)(b * 16 + c) * 1024 + blockIdx.x * 4 + wv] = s;
}

// ---------------- k2: reduce partials -> att ----------------
__global__ __launch_bounds__(1024) void k2_attention(
    const float* __restrict__ partials, const float* __restrict__ wsca,
    const float* __restrict__ bsca, float* __restrict__ att)
{
    __shared__ float red[32][32];
    __shared__ float gap[32];
    const int tid = threadIdx.x;
    {
        const int bc = tid >> 5, seg = tid & 31;
        float s = 0.f;
        const float* p = partials + (unsigned)bc * 1024 + seg * 32;
#pragma unroll
        for (int j = 0; j < 32; ++j) s += p[j];
        red[bc][seg] = s;
    }
    __syncthreads();
    if (tid < 32) {
        float s = 0.f;
#pragma unroll
        for (int g = 0; g < 32; ++g) s += red[tid][g];
        gap[tid] = s * GAP_INV;
    }
    __syncthreads();
    if (tid < 32) {
        const int b = tid >> 4, o = tid & 15;
        float acc = bsca[o];
#pragma unroll
        for (int c = 0; c < 16; ++c) acc = fmaf(wsca[o*16 + c], gap[b*16 + c], acc);
        att[b*16 + o] = fsigm(acc);
    }
}

// ---------------- k3: scale ----------------
// bf16-h path: read h (bf16, ws), write fp32 out. grid (248, 32) x 1024: exact.
__global__ __launch_bounds__(1024) void k3_scale_b(
    const unsigned short* __restrict__ hb, const float* __restrict__ att,
    float* __restrict__ out)
{
    const int bc = blockIdx.y;
    const float a = att[bc];
    const unsigned i = blockIdx.x * 1024 + threadIdx.x;     // < 253,952 = CS/8
    const size_t base = (size_t)bc * CS;
    const ushort8v v = ((const ushort8v*)(hb + base))[i];
    float4 o1, o2;
    o1.x = bf2f(v[0])*a; o1.y = bf2f(v[1])*a; o1.z = bf2f(v[2])*a; o1.w = bf2f(v[3])*a;
    o2.x = bf2f(v[4])*a; o2.y = bf2f(v[5])*a; o2.z = bf2f(v[6])*a; o2.w = bf2f(v[7])*a;
    float4* op = (float4*)(out + base);
    op[i*2]     = o1;
    op[i*2 + 1] = o2;
}

// fallback: in-place fp32 scale (h already resides in d_out)
__global__ __launch_bounds__(1024) void k3_scale_a(
    const float* __restrict__ att, float* __restrict__ out)
{
    const int bc = blockIdx.y;
    const float a = att[bc];
    const unsigned i = blockIdx.x * 1024 + threadIdx.x;
    float4* op = (float4*)(out + (size_t)bc * CS);
    float4 v1 = op[i*2], v2 = op[i*2 + 1];
    v1.x *= a; v1.y *= a; v1.z *= a; v1.w *= a;
    v2.x *= a; v2.y *= a; v2.z *= a; v2.w *= a;
    op[i*2] = v1; op[i*2 + 1] = v2;
}

extern "C" void kernel_launch(void* const* d_in, const int* in_sizes, int n_in,
                              void* d_out, int out_size, void* d_ws, size_t ws_size,
                              hipStream_t stream) {
    const float* x    = (const float*)d_in[0];
    const float* wf1  = (const float*)d_in[1];
    const float* bf1  = (const float*)d_in[2];
    const float* wf2  = (const float*)d_in[3];
    const float* bf2  = (const float*)d_in[4];
    const float* ww1  = (const float*)d_in[5];
    const float* bw1  = (const float*)d_in[6];
    const float* ww2  = (const float*)d_in[7];
    const float* bw2  = (const float*)d_in[8];
    const float* wsca = (const float*)d_in[9];
    const float* bsca = (const float*)d_in[10];
    float* out = (float*)d_out;

    const size_t hbBytes   = (size_t)NTOT * 2;               // 130,023,424
    const size_t partBytes = (size_t)32 * 1024 * 4;          // 131,072
    const bool bf16h = ws_size >= hbBytes + partBytes + 256;

    // d_out doubles as the gate buffer (u32 per element = exactly out_size);
    // kB consumes gates (and, in the fallback, overwrites them with f32 h);
    // k3 then fully overwrites d_out with the final scaled output.
    unsigned int* gates = (unsigned int*)d_out;
    unsigned short* hb = (unsigned short*)d_ws;
    float* partials = bf16h ? (float*)((char*)d_ws + hbBytes) : (float*)d_ws;
    float* att = partials + 32 * 1024;

    kA_gates<<<dim3(256, TDIM, 2), 256, 0, stream>>>(
        x, wf1, bf1, wf2, bf2, ww1, bw1, ww2, bw2, gates);

    if (bf16h) {
        kB_scan<true><<<dim3(256, 16, 2), 256, 0, stream>>>(gates, hb, partials);
        k2_attention<<<1, 1024, 0, stream>>>(partials, wsca, bsca, att);
        k3_scale_b<<<dim3(248, 32), 1024, 0, stream>>>(hb, att, out);
    } else {
        kB_scan<false><<<dim3(256, 16, 2), 256, 0, stream>>>(gates, hb, partials);
        k2_attention<<<1, 1024, 0, stream>>>(partials, wsca, bsca, att);
        k3_scale_a<<<dim3(248, 32), 1024, 0, stream>>>(att, out);
    }
}